// Round 21
// baseline (446.395 us; speedup 1.0000x reference)
//
#include <hip/hip_runtime.h>
#include <math.h>

#define NREG  8
#define HDIM  128
#define NDEPTH 3
#define TP    64      // points per workgroup tile (= lanes per wave)
#define W0F   30.0f
#define INV_2PI 0.15915494309189535f

// Inline HW sine: sin(y) = v_sin_f32(fract(y/2pi)) -- v_sin_f32 takes input
// in REVOLUTIONS (cdna4_isa.md), fract does the range reduction, periodicity
// makes it exact. Same math as OCML native sin but guaranteed inline
// (r20 post-mortem: __sinf emitted an s_swappc CALL -> 452us, VALUBusy 12%).
__device__ __forceinline__ float fast_sin(float y) {
    return __builtin_amdgcn_sinf(__builtin_amdgcn_fractf(y * INV_2PI));
}

// ---------------- routing helpers ----------------

__device__ __forceinline__ int region_of(float X, float Y, float Z, bool* valid) {
    *valid = (X >= 0.f) & (X <= 1.f) & (Y >= 0.f) & (Y <= 1.f) & (Z >= 0.f) & (Z <= 1.f);
    // box r = i*4 + j*2 + k ; ties at 0.5 belong to the lower box (argmax picks first)
    int i = (X > 0.5f) ? 1 : 0;
    int j = (Y > 0.5f) ? 1 : 0;
    int k = (Z > 0.5f) ? 1 : 0;
    return i * 4 + j * 2 + k;
}

// ws int layout: [0..7] counts, [8..16] offsets(exclusive, +total), [20..27] cursors
__global__ __launch_bounds__(256) void k_count(const float* __restrict__ x, int n,
                                               int* __restrict__ ws) {
    __shared__ int h[NREG];
    if (threadIdx.x < NREG) h[threadIdx.x] = 0;
    __syncthreads();
    int i = blockIdx.x * 256 + threadIdx.x;
    if (i < n) {
        float X = x[3*i], Y = x[3*i+1], Z = x[3*i+2];
        bool valid;
        int r = region_of(X, Y, Z, &valid);
        if (valid) atomicAdd(&h[r], 1);
    }
    __syncthreads();
    if (threadIdx.x < NREG) atomicAdd(&ws[threadIdx.x], h[threadIdx.x]);
}

__global__ void k_prefix(int* __restrict__ ws) {
    if (threadIdx.x == 0) {
        int acc = 0;
        for (int r = 0; r < NREG; ++r) {
            ws[8 + r] = acc;      // offsets
            ws[20 + r] = acc;     // cursors
            acc += ws[r];
        }
        ws[8 + NREG] = acc;
    }
}

// Block-aggregated scatter: LDS-rank within block, ONE global atomic per
// (block, region) chunk reservation, then direct stores.
__global__ __launch_bounds__(256) void k_scatter(const float* __restrict__ x, int n,
                                                 int* __restrict__ ws,
                                                 int* __restrict__ idx,
                                                 float* __restrict__ out) {
    __shared__ int hist[NREG];
    __shared__ int base[NREG];
    const int tid = threadIdx.x;
    if (tid < NREG) hist[tid] = 0;
    __syncthreads();
    int i = blockIdx.x * 256 + tid;
    int r = 0, rank = 0;
    bool valid = false;
    if (i < n) {
        float X = x[3*i], Y = x[3*i+1], Z = x[3*i+2];
        r = region_of(X, Y, Z, &valid);
        if (valid) rank = atomicAdd(&hist[r], 1);   // within-block rank
        else out[i] = 0.0f;   // points outside all boxes stay zero
    }
    __syncthreads();
    if (tid < NREG) {
        int c = hist[tid];
        base[tid] = c ? atomicAdd(&ws[20 + tid], c) : 0;
    }
    __syncthreads();
    if (valid) idx[base[r] + rank] = i;
}

// ---------------- fused per-region SIREN MLP ----------------
// EXACT r15 structure (best measured: 125.6us total, k_mlp 145.6us,
// VALUBusy 51%) with ONE change: sinf -> fast_sin (inline v_fract+v_sin,
// ~3 inst vs OCML sinf's ~50). Content audit: sinf was ~25us of the
// ~75us per-variant issue content, serial in the post-barrier phase.
// Numerics: identical math to OCML native sin -> expect absmax ~0.0566
// (r20 measured, passes 0.0687).

__global__ __launch_bounds__(512) void k_mlp(
    const float* __restrict__ x,
    const float* __restrict__ W_in,  const float* __restrict__ b_in,
    const float* __restrict__ W_h,   const float* __restrict__ b_h,
    const float* __restrict__ W_out, const float* __restrict__ b_out,
    const float* __restrict__ scale, const float* __restrict__ boxes,
    const int* __restrict__ offsets, const int* __restrict__ idx,
    float* __restrict__ out)
{
    __shared__ float hA[HDIM][TP];    // 32 KB [channel][point]
    __shared__ float part[8][TP];     // 2 KB

    const int tid  = threadIdx.x;
    const int wv   = tid >> 6;      // wave id 0..7 -> 16-channel chunk
    const int lane = tid & 63;      // point within tile
    const int k0   = __builtin_amdgcn_readfirstlane(wv << 4);  // SGPR chunk base

    // map flat block id -> (region, tile)
    int r = -1, base = 0, cnt = 0;
    {
        int bid = blockIdx.x, acc0 = 0;
        for (int rr = 0; rr < NREG; ++rr) {
            int o0 = offsets[rr], o1 = offsets[rr + 1];
            int c = o1 - o0;
            int t = (c + TP - 1) / TP;
            if (bid < acc0 + t) {
                int tile = bid - acc0;
                r = rr; base = o0 + tile * TP; cnt = c - tile * TP;
                break;
            }
            acc0 += t;
        }
    }
    if (r < 0) return;                 // uniform across the block
    if (cnt > TP) cnt = TP;

    // ---- per-lane point & normalized coords ----
    int g = (lane < cnt) ? idx[base + lane] : -1;
    float xn0 = 0.f, xn1 = 0.f, xn2 = 0.f;
    if (g >= 0) {
        float lo0 = boxes[r*6 + 0], hi0 = boxes[r*6 + 1];
        float lo1 = boxes[r*6 + 2], hi1 = boxes[r*6 + 3];
        float lo2 = boxes[r*6 + 4], hi2 = boxes[r*6 + 5];
        xn0 = (2.0f * (x[3*g+0] - lo0) / (hi0 - lo0) - 1.0f) * scale[r*3 + 0];
        xn1 = (2.0f * (x[3*g+1] - lo1) / (hi1 - lo1) - 1.0f) * scale[r*3 + 1];
        xn2 = (2.0f * (x[3*g+2] - lo2) / (hi2 - lo2) - 1.0f) * scale[r*3 + 2];
    }

    // ---- input layer: hA[k][lane] = sin(30*(xn . W_in[:,k] + b_in[k])) ----
    {
        const float* Wr = W_in + r * 3 * HDIM + k0;   // uniform base -> s_load
        const float* br = b_in + r * HDIM + k0;
        #pragma unroll
        for (int c = 0; c < 16; ++c) {
            float pre = fmaf(xn0, Wr[0*HDIM + c],
                        fmaf(xn1, Wr[1*HDIM + c],
                        fmaf(xn2, Wr[2*HDIM + c], br[c])));
            hA[k0 + c][lane] = fast_sin(W0F * pre);
        }
    }
    __syncthreads();

    // ---- hidden layers ----
    for (int l = 0; l < NDEPTH; ++l) {
        const float* Wl = W_h + ((size_t)(r * NDEPTH + l)) * HDIM * HDIM + k0;
        const float* bl = b_h + (r * NDEPTH + l) * HDIM + k0;
        float acc[16];
        #pragma unroll
        for (int c = 0; c < 16; ++c) acc[c] = bl[c];   // bias-init (scalar load)

        #pragma unroll 4
        for (int j = 0; j < HDIM; ++j) {
            float a = hA[j][lane];                      // 1 ds_read_b32 / wave / j
            const float* wrow = Wl + (size_t)j * HDIM;  // uniform row -> s_load_x16
            #pragma unroll
            for (int c = 0; c < 16; ++c)
                acc[c] = fmaf(wrow[c], a, acc[c]);      // v_fmac with SGPR weight
        }
        // sin in registers (inline v_fract + v_sin), then overwrite hA
        #pragma unroll
        for (int c = 0; c < 16; ++c) acc[c] = fast_sin(W0F * acc[c]);
        __syncthreads();   // all waves finished reading hA
        #pragma unroll
        for (int c = 0; c < 16; ++c) hA[k0 + c][lane] = acc[c];
        __syncthreads();   // writes visible before next layer reads
    }

    // ---- output layer: partial dot per 16-ch chunk, reduce via LDS ----
    {
        const float* Wo = W_out + r * HDIM + k0;       // uniform -> s_load
        float s = 0.f;
        #pragma unroll
        for (int c = 0; c < 16; ++c)
            s = fmaf(Wo[c], hA[k0 + c][lane], s);
        part[wv][lane] = s;
    }
    __syncthreads();
    if (wv == 0) {
        float s = part[0][lane] + part[1][lane] + part[2][lane] + part[3][lane]
                + part[4][lane] + part[5][lane] + part[6][lane] + part[7][lane]
                + b_out[r];
        if (g >= 0) out[g] = s;
    }
}

// ---------------- launcher ----------------

extern "C" void kernel_launch(void* const* d_in, const int* in_sizes, int n_in,
                              void* d_out, int out_size, void* d_ws, size_t ws_size,
                              hipStream_t stream) {
    const float* x      = (const float*)d_in[0];
    const float* W_in   = (const float*)d_in[1];
    const float* b_in   = (const float*)d_in[2];
    const float* W_h    = (const float*)d_in[3];
    const float* b_h    = (const float*)d_in[4];
    const float* W_out  = (const float*)d_in[5];
    const float* b_out  = (const float*)d_in[6];
    const float* scale  = (const float*)d_in[7];
    const float* boxes  = (const float*)d_in[8];
    float* out = (float*)d_out;

    int n = in_sizes[0] / 3;
    int* wsi = (int*)d_ws;
    int* idx = (int*)((char*)d_ws + 256);

    hipMemsetAsync(d_ws, 0, 256, stream);

    int nb = (n + 255) / 256;
    hipLaunchKernelGGL(k_count,   dim3(nb), dim3(256), 0, stream, x, n, wsi);
    hipLaunchKernelGGL(k_prefix,  dim3(1),  dim3(64),  0, stream, wsi);
    hipLaunchKernelGGL(k_scatter, dim3(nb), dim3(256), 0, stream, x, n, wsi, idx, out);

    int ntiles = (n + TP - 1) / TP + NREG;
    hipLaunchKernelGGL(k_mlp, dim3(ntiles), dim3(512), 0, stream,
                       x, W_in, b_in, W_h, b_h, W_out, b_out, scale, boxes,
                       wsi + 8, idx, out);
}

// Round 22
// 143.012 us; speedup vs baseline: 3.1214x; 3.1214x over previous
//
#include <hip/hip_runtime.h>
#include <math.h>

#define NREG  8
#define HDIM  128
#define NDEPTH 3
#define TP    64      // points per workgroup tile (= lanes per wave)
#define W0F   30.0f

// ---------------- routing helpers ----------------

__device__ __forceinline__ int region_of(float X, float Y, float Z, bool* valid) {
    *valid = (X >= 0.f) & (X <= 1.f) & (Y >= 0.f) & (Y <= 1.f) & (Z >= 0.f) & (Z <= 1.f);
    // box r = i*4 + j*2 + k ; ties at 0.5 belong to the lower box (argmax picks first)
    int i = (X > 0.5f) ? 1 : 0;
    int j = (Y > 0.5f) ? 1 : 0;
    int k = (Z > 0.5f) ? 1 : 0;
    return i * 4 + j * 2 + k;
}

// ws int layout: [0..7] counts, [8..16] offsets(exclusive, +total), [20..27] cursors
__global__ __launch_bounds__(256) void k_count(const float* __restrict__ x, int n,
                                               int* __restrict__ ws) {
    __shared__ int h[NREG];
    if (threadIdx.x < NREG) h[threadIdx.x] = 0;
    __syncthreads();
    int i = blockIdx.x * 256 + threadIdx.x;
    if (i < n) {
        float X = x[3*i], Y = x[3*i+1], Z = x[3*i+2];
        bool valid;
        int r = region_of(X, Y, Z, &valid);
        if (valid) atomicAdd(&h[r], 1);
    }
    __syncthreads();
    if (threadIdx.x < NREG) atomicAdd(&ws[threadIdx.x], h[threadIdx.x]);
}

__global__ void k_prefix(int* __restrict__ ws) {
    if (threadIdx.x == 0) {
        int acc = 0;
        for (int r = 0; r < NREG; ++r) {
            ws[8 + r] = acc;      // offsets
            ws[20 + r] = acc;     // cursors
            acc += ws[r];
        }
        ws[8 + NREG] = acc;
    }
}

// Block-aggregated scatter: LDS-rank within block, ONE global atomic per
// (block, region) chunk reservation, then direct stores.
__global__ __launch_bounds__(256) void k_scatter(const float* __restrict__ x, int n,
                                                 int* __restrict__ ws,
                                                 int* __restrict__ idx,
                                                 float* __restrict__ out) {
    __shared__ int hist[NREG];
    __shared__ int base[NREG];
    const int tid = threadIdx.x;
    if (tid < NREG) hist[tid] = 0;
    __syncthreads();
    int i = blockIdx.x * 256 + tid;
    int r = 0, rank = 0;
    bool valid = false;
    if (i < n) {
        float X = x[3*i], Y = x[3*i+1], Z = x[3*i+2];
        r = region_of(X, Y, Z, &valid);
        if (valid) rank = atomicAdd(&hist[r], 1);   // within-block rank
        else out[i] = 0.0f;   // points outside all boxes stay zero
    }
    __syncthreads();
    if (tid < NREG) {
        int c = hist[tid];
        base[tid] = c ? atomicAdd(&ws[20 + tid], c) : 0;
    }
    __syncthreads();
    if (valid) idx[base[r] + rank] = i;
}

// ---------------- fused per-region SIREN MLP ----------------
// r15 structure (512 thr = 8 waves, 16 ch/wave, hA 32KB, 4 blocks/CU,
// weights via wave-uniform s_load_dwordx16, OCML sinf) + EXPLICIT 4-row
// s_load batching: load rows j..j+3 into named locals BEFORE any FMA, so
// 4x s_load_dwordx16 + 4 ds_read issue together and drain ONCE per 4 j.
// r20/r21 post-mortem: v_sin variants perturbed the scheduler into
// single-buffered per-j drains (SGPR 112->80, VALUBusy 51->12%, 3x slower)
// -- s_load pipelining depth is allocator-dependent; force it from source,
// and keep sinf (its schedule is the proven-good one).
// FMA order (j ascending per channel) unchanged -> absmax 0.04919434 exact.

__global__ __launch_bounds__(512) void k_mlp(
    const float* __restrict__ x,
    const float* __restrict__ W_in,  const float* __restrict__ b_in,
    const float* __restrict__ W_h,   const float* __restrict__ b_h,
    const float* __restrict__ W_out, const float* __restrict__ b_out,
    const float* __restrict__ scale, const float* __restrict__ boxes,
    const int* __restrict__ offsets, const int* __restrict__ idx,
    float* __restrict__ out)
{
    __shared__ float hA[HDIM][TP];    // 32 KB [channel][point]
    __shared__ float part[8][TP];     // 2 KB

    const int tid  = threadIdx.x;
    const int wv   = tid >> 6;      // wave id 0..7 -> 16-channel chunk
    const int lane = tid & 63;      // point within tile
    const int k0   = __builtin_amdgcn_readfirstlane(wv << 4);  // SGPR chunk base

    // map flat block id -> (region, tile)
    int r = -1, base = 0, cnt = 0;
    {
        int bid = blockIdx.x, acc0 = 0;
        for (int rr = 0; rr < NREG; ++rr) {
            int o0 = offsets[rr], o1 = offsets[rr + 1];
            int c = o1 - o0;
            int t = (c + TP - 1) / TP;
            if (bid < acc0 + t) {
                int tile = bid - acc0;
                r = rr; base = o0 + tile * TP; cnt = c - tile * TP;
                break;
            }
            acc0 += t;
        }
    }
    if (r < 0) return;                 // uniform across the block
    if (cnt > TP) cnt = TP;

    // ---- per-lane point & normalized coords ----
    int g = (lane < cnt) ? idx[base + lane] : -1;
    float xn0 = 0.f, xn1 = 0.f, xn2 = 0.f;
    if (g >= 0) {
        float lo0 = boxes[r*6 + 0], hi0 = boxes[r*6 + 1];
        float lo1 = boxes[r*6 + 2], hi1 = boxes[r*6 + 3];
        float lo2 = boxes[r*6 + 4], hi2 = boxes[r*6 + 5];
        xn0 = (2.0f * (x[3*g+0] - lo0) / (hi0 - lo0) - 1.0f) * scale[r*3 + 0];
        xn1 = (2.0f * (x[3*g+1] - lo1) / (hi1 - lo1) - 1.0f) * scale[r*3 + 1];
        xn2 = (2.0f * (x[3*g+2] - lo2) / (hi2 - lo2) - 1.0f) * scale[r*3 + 2];
    }

    // ---- input layer: hA[k][lane] = sin(30*(xn . W_in[:,k] + b_in[k])) ----
    {
        const float* Wr = W_in + r * 3 * HDIM + k0;   // uniform base -> s_load
        const float* br = b_in + r * HDIM + k0;
        #pragma unroll
        for (int c = 0; c < 16; ++c) {
            float pre = fmaf(xn0, Wr[0*HDIM + c],
                        fmaf(xn1, Wr[1*HDIM + c],
                        fmaf(xn2, Wr[2*HDIM + c], br[c])));
            hA[k0 + c][lane] = sinf(W0F * pre);
        }
    }
    __syncthreads();

    // ---- hidden layers (explicit 4-row s_load batching) ----
    for (int l = 0; l < NDEPTH; ++l) {
        const float* Wl = W_h + ((size_t)(r * NDEPTH + l)) * HDIM * HDIM + k0;
        const float* bl = b_h + (r * NDEPTH + l) * HDIM + k0;
        float acc[16];
        #pragma unroll
        for (int c = 0; c < 16; ++c) acc[c] = bl[c];   // bias-init (scalar load)

        #pragma unroll 2
        for (int jb = 0; jb < HDIM; jb += 4) {
            // batch-issue: 4 uniform weight rows (4x s_load_dwordx16)
            const float* r0 = Wl + (size_t)(jb + 0) * HDIM;
            const float* r1 = Wl + (size_t)(jb + 1) * HDIM;
            const float* r2 = Wl + (size_t)(jb + 2) * HDIM;
            const float* r3 = Wl + (size_t)(jb + 3) * HDIM;
            float w0[16], w1[16], w2[16], w3[16];
            #pragma unroll
            for (int c = 0; c < 16; ++c) {
                w0[c] = r0[c]; w1[c] = r1[c]; w2[c] = r2[c]; w3[c] = r3[c];
            }
            // + 4 activation reads (ds_read_b32), same drain
            float a0 = hA[jb + 0][lane];
            float a1 = hA[jb + 1][lane];
            float a2 = hA[jb + 2][lane];
            float a3 = hA[jb + 3][lane];
            // dense FMA issue: 64 FMA per drain (j ascending per channel)
            #pragma unroll
            for (int c = 0; c < 16; ++c) acc[c] = fmaf(w0[c], a0, acc[c]);
            #pragma unroll
            for (int c = 0; c < 16; ++c) acc[c] = fmaf(w1[c], a1, acc[c]);
            #pragma unroll
            for (int c = 0; c < 16; ++c) acc[c] = fmaf(w2[c], a2, acc[c]);
            #pragma unroll
            for (int c = 0; c < 16; ++c) acc[c] = fmaf(w3[c], a3, acc[c]);
        }

        // sin in registers, then in-place overwrite of hA
        #pragma unroll
        for (int c = 0; c < 16; ++c) acc[c] = sinf(W0F * acc[c]);
        __syncthreads();   // all waves finished reading hA
        #pragma unroll
        for (int c = 0; c < 16; ++c) hA[k0 + c][lane] = acc[c];
        __syncthreads();   // writes visible before next layer reads
    }

    // ---- output layer: partial dot per 16-ch chunk, reduce via LDS ----
    {
        const float* Wo = W_out + r * HDIM + k0;       // uniform -> s_load
        float s = 0.f;
        #pragma unroll
        for (int c = 0; c < 16; ++c)
            s = fmaf(Wo[c], hA[k0 + c][lane], s);
        part[wv][lane] = s;
    }
    __syncthreads();
    if (wv == 0) {
        float s = part[0][lane] + part[1][lane] + part[2][lane] + part[3][lane]
                + part[4][lane] + part[5][lane] + part[6][lane] + part[7][lane]
                + b_out[r];
        if (g >= 0) out[g] = s;
    }
}

// ---------------- launcher ----------------

extern "C" void kernel_launch(void* const* d_in, const int* in_sizes, int n_in,
                              void* d_out, int out_size, void* d_ws, size_t ws_size,
                              hipStream_t stream) {
    const float* x      = (const float*)d_in[0];
    const float* W_in   = (const float*)d_in[1];
    const float* b_in   = (const float*)d_in[2];
    const float* W_h    = (const float*)d_in[3];
    const float* b_h    = (const float*)d_in[4];
    const float* W_out  = (const float*)d_in[5];
    const float* b_out  = (const float*)d_in[6];
    const float* scale  = (const float*)d_in[7];
    const float* boxes  = (const float*)d_in[8];
    float* out = (float*)d_out;

    int n = in_sizes[0] / 3;
    int* wsi = (int*)d_ws;
    int* idx = (int*)((char*)d_ws + 256);

    hipMemsetAsync(d_ws, 0, 256, stream);

    int nb = (n + 255) / 256;
    hipLaunchKernelGGL(k_count,   dim3(nb), dim3(256), 0, stream, x, n, wsi);
    hipLaunchKernelGGL(k_prefix,  dim3(1),  dim3(64),  0, stream, wsi);
    hipLaunchKernelGGL(k_scatter, dim3(nb), dim3(256), 0, stream, x, n, wsi, idx, out);

    int ntiles = (n + TP - 1) / TP + NREG;
    hipLaunchKernelGGL(k_mlp, dim3(ntiles), dim3(512), 0, stream,
                       x, W_in, b_in, W_h, b_h, W_out, b_out, scale, boxes,
                       wsi + 8, idx, out);
}